// Round 5
// baseline (127.214 us; speedup 1.0000x reference)
//
#include <hip/hip_runtime.h>
#include <hip/hip_bf16.h>

// AdaptiveGraphNetwork via MFMA 16x16x32 bf16. B=4096, N=64, D=32, H=64.
// Two kernels per launch:
//  (1) agn_prep: repack all weights into d_ws as bf16 MFMA B-fragments,
//      fragment-ordered so the main kernel loads each fragment as ONE
//      coalesced 16B/lane global load (L2-hot, shared by all WGs).
//      Also stages biases (fragment-ordered f32) and rw.
//  (2) agn_main: one batch per WG (4096 WGs), single pass, 3 barriers.
//      Phase A: h[e]  = relu(x[dst]@Wm1_t + x[src]@Wm1_b + bm1)   (gathered from global)
//      Phase B: msgb  = relu(h @ Wm2 + bm2)
//      Phase C: hu    = relu([x | scatter(msgb)] @ Wu1 + bu1)
//      Phase D: out   = rw*(hu @ Wu2 + bu2) + (1-rw)*x
// Fragment maps (m89/m91-verified): A[m=lane&15][k=quad*8+j],
// B[k=quad*8+j][n=lane&15], C/D[row=quad*4+reg][col=lane&15].
//
// ws layout: [0,24576) 24 bf16 frags x 512 (lane*8+j);
//            [24576,25344) 192 f32 biases (12 groups x 16, idx=g*16+(lane&15));
//            [25344,25348) f32 rw.

typedef __bf16 bf16x8 __attribute__((ext_vector_type(8)));
typedef float  f32x4  __attribute__((ext_vector_type(4)));
typedef unsigned short u16;

#define HS  72   // sH row stride in u16 (144 B)
#define MBS 40   // sMB row stride in u16 (80 B)

__device__ __forceinline__ u16 f2b(float f) { return __builtin_bit_cast(u16, (__bf16)f); }
__device__ __forceinline__ f32x4 MFMA(bf16x8 a, bf16x8 b, f32x4 c) {
    return __builtin_amdgcn_mfma_f32_16x16x32_bf16(a, b, c, 0, 0, 0);
}
__device__ __forceinline__ bf16x8 pack8(float4 a, float4 b) {
    bf16x8 r = {(__bf16)a.x, (__bf16)a.y, (__bf16)a.z, (__bf16)a.w,
                (__bf16)b.x, (__bf16)b.y, (__bf16)b.z, (__bf16)b.w};
    return r;
}

// ---------------- prep: weight repack (48 blocks x 256 thr) ----------------
__global__ void agn_prep(const float* __restrict__ Wm1, const float* __restrict__ bm1,
                         const float* __restrict__ Wm2, const float* __restrict__ bm2,
                         const float* __restrict__ Wu1, const float* __restrict__ bu1,
                         const float* __restrict__ Wu2, const float* __restrict__ bu2,
                         const float* __restrict__ rw,
                         u16* __restrict__ wsf, float* __restrict__ wsb)
{
    const int idx = blockIdx.x * 256 + threadIdx.x;   // 0..12287
    {
        const int f = idx >> 9, r = idx & 511;
        const int lane = r >> 3, j = r & 7;
        const int ln = lane & 15, q = lane >> 4;
        float v;
        if (f < 4)       v = Wm1[(q * 8 + j) * 64 + f * 16 + ln];
        else if (f < 8)  v = Wm1[(32 + q * 8 + j) * 64 + (f - 4) * 16 + ln];
        else if (f < 12) { int s = (f - 8) >> 1, nt = (f - 8) & 1;  v = Wm2[(s * 32 + q * 8 + j) * 32 + nt * 16 + ln]; }
        else if (f < 20) { int s = (f - 12) >> 2, nt = (f - 12) & 3; v = Wu1[(s * 32 + q * 8 + j) * 64 + nt * 16 + ln]; }
        else             { int s = (f - 20) >> 1, nt = (f - 20) & 1; v = Wu2[(s * 32 + q * 8 + j) * 32 + nt * 16 + ln]; }
        wsf[idx] = f2b(v);
    }
    if (blockIdx.x == 0) {
        const int t = threadIdx.x;
        if (t < 192) {
            const int g = t >> 4, i = t & 15;
            float v;
            if (g < 4)       v = bm1[g * 16 + i];
            else if (g < 6)  v = bm2[(g - 4) * 16 + i];
            else if (g < 10) v = bu1[(g - 6) * 16 + i];
            else             v = bu2[(g - 10) * 16 + i];
            wsb[t] = v;
        }
        if (t == 255) wsb[192] = rw[0];
    }
}

// ---------------- main: one batch per WG ----------------
__global__ __launch_bounds__(256, 4)
void agn_main(const float* __restrict__ x, const u16* __restrict__ wsf,
              const float* __restrict__ wsb, float* __restrict__ out)
{
    __shared__ __align__(16) u16 sH[128 * HS];    // 18432 B (edge-h; rows 0..63 reused as hu)
    __shared__ __align__(16) u16 sMB[128 * MBS];  // 10240 B

    const int t = threadIdx.x;
    const int w = t >> 6;
    const int lane = t & 63;
    const int ln = lane & 15;
    const int q  = lane >> 4;

    const size_t base = (size_t)blockIdx.x * (64 * 32);
    const float* xb = x + base;
    float*       ob = out + base;

    const u16* wf = wsf + lane * 8;
#define LDFRAG(f) __builtin_bit_cast(bf16x8, *(const uint4*)(wf + ((f) << 9)))

    // ===== Phase A: h[e] = relu(x[dst]@Wm1_t + x[src]@Wm1_b + bm1) =====
    {
        bf16x8 B1a[4], B1b[4];
#pragma unroll
        for (int nt = 0; nt < 4; ++nt) { B1a[nt] = LDFRAG(nt); B1b[nt] = LDFRAG(4 + nt); }
        float bm1v[4];
#pragma unroll
        for (int nt = 0; nt < 4; ++nt) bm1v[nt] = wsb[nt * 16 + ln];
#pragma unroll
        for (int m = 0; m < 2; ++m) {
            const int mt = 2 * w + m;          // 0..7
            int e = mt * 16 + ln;              // 0..127
            if (e >= 126) e = 0;               // pad rows: computed, never read
            const int dst  = (e < 63) ? e : e - 62;
            const int srcn = (e < 63) ? e + 1 : e - 63;
            const float* pd = xb + dst * 32 + q * 8;
            const float* ps = xb + srcn * 32 + q * 8;
            float4 d0 = *(const float4*)pd, d1 = *(const float4*)(pd + 4);
            float4 s0 = *(const float4*)ps, s1 = *(const float4*)(ps + 4);
            bf16x8 Ad = pack8(d0, d1);
            bf16x8 As = pack8(s0, s1);
#pragma unroll
            for (int nt = 0; nt < 4; ++nt) {
                f32x4 acc = {0.f, 0.f, 0.f, 0.f};
                acc = MFMA(Ad, B1a[nt], acc);
                acc = MFMA(As, B1b[nt], acc);
                const int rb = mt * 16 + q * 4;
                const int c  = nt * 16 + ln;
#pragma unroll
                for (int r = 0; r < 4; ++r)
                    sH[(rb + r) * HS + c] = f2b(fmaxf(acc[r] + bm1v[nt], 0.f));
            }
        }
    }
    __syncthreads();

    // ===== Phase B: msgb = relu(h @ Wm2 + bm2) =====
    {
        bf16x8 B2[2][2];
#pragma unroll
        for (int s = 0; s < 2; ++s)
#pragma unroll
            for (int nt = 0; nt < 2; ++nt) B2[s][nt] = LDFRAG(8 + s * 2 + nt);
        float bm2v[2] = { wsb[64 + ln], wsb[80 + ln] };
#pragma unroll
        for (int m = 0; m < 2; ++m) {
            const int mt = 2 * w + m;
            const int row = mt * 16 + ln;
            bf16x8 A0 = __builtin_bit_cast(bf16x8, *(const uint4*)&sH[row * HS + q * 8]);
            bf16x8 A1 = __builtin_bit_cast(bf16x8, *(const uint4*)&sH[row * HS + 32 + q * 8]);
#pragma unroll
            for (int nt = 0; nt < 2; ++nt) {
                f32x4 acc = {0.f, 0.f, 0.f, 0.f};
                acc = MFMA(A0, B2[0][nt], acc);
                acc = MFMA(A1, B2[1][nt], acc);
                const int rb = mt * 16 + q * 4;
                const int c  = nt * 16 + ln;
#pragma unroll
                for (int r = 0; r < 4; ++r)
                    sMB[(rb + r) * MBS + c] = f2b(fmaxf(acc[r] + bm2v[nt], 0.f));
            }
        }
    }
    __syncthreads();

    // ===== Phase C: hu = relu([x | scatter(msgb)] @ Wu1 + bu1) =====
    {
        bf16x8 B3[2][4];
#pragma unroll
        for (int s = 0; s < 2; ++s)
#pragma unroll
            for (int nt = 0; nt < 4; ++nt) B3[s][nt] = LDFRAG(12 + s * 4 + nt);
        float bu1v[4];
#pragma unroll
        for (int nt = 0; nt < 4; ++nt) bu1v[nt] = wsb[96 + nt * 16 + ln];
        const int row = w * 16 + ln;          // 0..63
        const float* p = xb + row * 32 + q * 8;
        float4 a0 = *(const float4*)p, a1 = *(const float4*)(p + 4);
        bf16x8 A0 = pack8(a0, a1);
        float mv[8] = {0.f, 0.f, 0.f, 0.f, 0.f, 0.f, 0.f, 0.f};
        if (row < 63) {
            uint4 u = *(const uint4*)&sMB[row * MBS + q * 8];
            const unsigned* pu = (const unsigned*)&u;
#pragma unroll
            for (int h = 0; h < 4; ++h) {
                mv[2 * h]     += __uint_as_float(pu[h] << 16);
                mv[2 * h + 1] += __uint_as_float(pu[h] & 0xFFFF0000u);
            }
        }
        if (row > 0) {
            uint4 u = *(const uint4*)&sMB[(62 + row) * MBS + q * 8];
            const unsigned* pu = (const unsigned*)&u;
#pragma unroll
            for (int h = 0; h < 4; ++h) {
                mv[2 * h]     += __uint_as_float(pu[h] << 16);
                mv[2 * h + 1] += __uint_as_float(pu[h] & 0xFFFF0000u);
            }
        }
        bf16x8 A1;
#pragma unroll
        for (int j = 0; j < 8; ++j) A1[j] = (__bf16)mv[j];
#pragma unroll
        for (int nt = 0; nt < 4; ++nt) {
            f32x4 acc = {0.f, 0.f, 0.f, 0.f};
            acc = MFMA(A0, B3[0][nt], acc);
            acc = MFMA(A1, B3[1][nt], acc);
            const int rb = w * 16 + q * 4;    // hu rows 0..63 (alias over dead edge-h)
            const int c  = nt * 16 + ln;
#pragma unroll
            for (int r = 0; r < 4; ++r)
                sH[(rb + r) * HS + c] = f2b(fmaxf(acc[r] + bu1v[nt], 0.f));
        }
    }
    __syncthreads();

    // ===== Phase D: out = rw*(hu @ Wu2 + bu2) + (1-rw)*x =====
    {
        bf16x8 B4[2][2];
#pragma unroll
        for (int s = 0; s < 2; ++s)
#pragma unroll
            for (int nt = 0; nt < 2; ++nt) B4[s][nt] = LDFRAG(20 + s * 2 + nt);
        float bu2v[2] = { wsb[160 + ln], wsb[176 + ln] };
        const float rw = wsb[192];
        const float om = 1.f - rw;
        const int arow = w * 16 + ln;
        bf16x8 A0 = __builtin_bit_cast(bf16x8, *(const uint4*)&sH[arow * HS + q * 8]);
        bf16x8 A1 = __builtin_bit_cast(bf16x8, *(const uint4*)&sH[arow * HS + 32 + q * 8]);
#pragma unroll
        for (int nt = 0; nt < 2; ++nt) {
            f32x4 acc = {0.f, 0.f, 0.f, 0.f};
            acc = MFMA(A0, B4[0][nt], acc);
            acc = MFMA(A1, B4[1][nt], acc);
            const int rb = w * 16 + q * 4;
            const int c  = nt * 16 + ln;
#pragma unroll
            for (int r = 0; r < 4; ++r) {
                const int off = (rb + r) * 32 + c;
                ob[off] = rw * (acc[r] + bu2v[nt]) + om * xb[off];
            }
        }
    }
#undef LDFRAG
}

extern "C" void kernel_launch(void* const* d_in, const int* in_sizes, int n_in,
                              void* d_out, int out_size, void* d_ws, size_t ws_size,
                              hipStream_t stream) {
    const float* x   = (const float*)d_in[0];
    const float* Wm1 = (const float*)d_in[1];
    const float* bm1 = (const float*)d_in[2];
    const float* Wm2 = (const float*)d_in[3];
    const float* bm2 = (const float*)d_in[4];
    const float* Wu1 = (const float*)d_in[5];
    const float* bu1 = (const float*)d_in[6];
    const float* Wu2 = (const float*)d_in[7];
    const float* bu2 = (const float*)d_in[8];
    const float* rw  = (const float*)d_in[9];
    float* out = (float*)d_out;

    u16*   wsf = (u16*)d_ws;
    float* wsb = (float*)((char*)d_ws + 24576);

    const int B = in_sizes[0] / (64 * 32);
    agn_prep<<<48, 256, 0, stream>>>(Wm1, bm1, Wm2, bm2, Wu1, bu1, Wu2, bu2, rw, wsf, wsb);
    agn_main<<<B, 256, 0, stream>>>(x, wsf, wsb, out);
}

// Round 6
// 124.073 us; speedup vs baseline: 1.0253x; 1.0253x over previous
//
#include <hip/hip_runtime.h>
#include <hip/hip_bf16.h>

// AdaptiveGraphNetwork via MFMA 16x16x32 bf16. B=4096, N=64, D=32, H=64.
// Round-6 structure: ONE BATCH PER WAVE, ZERO __syncthreads().
// Each wave owns a private LDS slice (16x64 bf16 patch + 128x32 bf16 msgb);
// all producer->consumer LDS traffic is same-wave (lgkmcnt-ordered), so the
// 4 phases of a batch form one dependency chain with no cross-wave barriers.
// ~12 independent wave-chains per CU hide each other's latency.
//
//  prep: repack weights into d_ws as fragment-ordered bf16 (1 coalesced
//        16B/lane load per fragment in main; L1-hot, rewritten every launch
//        because the harness re-poisons d_ws).
//  main, per wave/batch:
//   per edge-tile et(8): A: h = relu(x[dst]@Wm1_t + x[src]@Wm1_b + bm1)
//                        -> patch -> B: msgb = relu(h @ Wm2 + bm2) -> mb
//   per node-tile nt4(4): C: hu = relu([x | mb[i]+mb[62+i]] @ Wu1 + bu1)
//                        -> patch -> D: out = rw*(hu @ Wu2 + bu2) + (1-rw)*x
// Fragment maps (m89/m91-verified): A[m=lane&15][k=quad*8+j],
// B[k=quad*8+j][n=lane&15], C/D[row=quad*4+reg][col=lane&15].

typedef __bf16 bf16x8 __attribute__((ext_vector_type(8)));
typedef float  f32x4  __attribute__((ext_vector_type(4)));
typedef unsigned short u16;

#define PS  72   // patch row stride in u16 (144 B, 16B-aligned, odd/2-way banks)
#define MBS 40   // msgb row stride in u16 (80 B)

__device__ __forceinline__ u16 f2b(float f) { return __builtin_bit_cast(u16, (__bf16)f); }
__device__ __forceinline__ f32x4 MFMA(bf16x8 a, bf16x8 b, f32x4 c) {
    return __builtin_amdgcn_mfma_f32_16x16x32_bf16(a, b, c, 0, 0, 0);
}
__device__ __forceinline__ bf16x8 pack8(float4 a, float4 b) {
    bf16x8 r = {(__bf16)a.x, (__bf16)a.y, (__bf16)a.z, (__bf16)a.w,
                (__bf16)b.x, (__bf16)b.y, (__bf16)b.z, (__bf16)b.w};
    return r;
}

// ---------------- prep: weight repack (48 blocks x 256 thr) ----------------
__global__ void agn_prep(const float* __restrict__ Wm1, const float* __restrict__ bm1,
                         const float* __restrict__ Wm2, const float* __restrict__ bm2,
                         const float* __restrict__ Wu1, const float* __restrict__ bu1,
                         const float* __restrict__ Wu2, const float* __restrict__ bu2,
                         const float* __restrict__ rw,
                         u16* __restrict__ wsf, float* __restrict__ wsb)
{
    const int idx = blockIdx.x * 256 + threadIdx.x;   // 0..12287
    {
        const int f = idx >> 9, r = idx & 511;
        const int lane = r >> 3, j = r & 7;
        const int ln = lane & 15, q = lane >> 4;
        float v;
        if (f < 4)       v = Wm1[(q * 8 + j) * 64 + f * 16 + ln];
        else if (f < 8)  v = Wm1[(32 + q * 8 + j) * 64 + (f - 4) * 16 + ln];
        else if (f < 12) { int s = (f - 8) >> 1, nt = (f - 8) & 1;  v = Wm2[(s * 32 + q * 8 + j) * 32 + nt * 16 + ln]; }
        else if (f < 20) { int s = (f - 12) >> 2, nt = (f - 12) & 3; v = Wu1[(s * 32 + q * 8 + j) * 64 + nt * 16 + ln]; }
        else             { int s = (f - 20) >> 1, nt = (f - 20) & 1; v = Wu2[(s * 32 + q * 8 + j) * 32 + nt * 16 + ln]; }
        wsf[idx] = f2b(v);
    }
    if (blockIdx.x == 0) {
        const int t = threadIdx.x;
        if (t < 192) {
            const int g = t >> 4, i = t & 15;
            float v;
            if (g < 4)       v = bm1[g * 16 + i];
            else if (g < 6)  v = bm2[(g - 4) * 16 + i];
            else if (g < 10) v = bu1[(g - 6) * 16 + i];
            else             v = bu2[(g - 10) * 16 + i];
            wsb[t] = v;
        }
        if (t == 255) wsb[192] = rw[0];
    }
}

// ---------------- main: one batch per WAVE, no barriers ----------------
__global__ __launch_bounds__(256, 3)
void agn_main(const float* __restrict__ x, const u16* __restrict__ wsf,
              const float* __restrict__ wsb, float* __restrict__ out)
{
    __shared__ __align__(16) u16 sPatch[4][16 * PS];   // 4 x 2304 B
    __shared__ __align__(16) u16 sMB[4][128 * MBS];    // 4 x 10240 B  (total 50176 B)

    const int t = threadIdx.x;
    const int w = t >> 6;
    const int lane = t & 63;
    const int ln = lane & 15;
    const int q  = lane >> 4;

    u16* patch = sPatch[w];
    u16* mb    = sMB[w];

    const size_t base = ((size_t)blockIdx.x * 4 + w) * (64 * 32);
    const float* xb = x + base;
    float*       ob = out + base;

    const u16* wf = wsf + lane * 8;
#define LDFRAG(f) __builtin_bit_cast(bf16x8, *(const uint4*)(wf + ((f) << 9)))

    // ===== Phases A+B, fused per 16-edge tile =====
    {
        bf16x8 B1a[4], B1b[4], B2[2][2];
#pragma unroll
        for (int nt = 0; nt < 4; ++nt) { B1a[nt] = LDFRAG(nt); B1b[nt] = LDFRAG(4 + nt); }
#pragma unroll
        for (int s = 0; s < 2; ++s)
#pragma unroll
            for (int nt = 0; nt < 2; ++nt) B2[s][nt] = LDFRAG(8 + s * 2 + nt);
        float bm1v[4];
#pragma unroll
        for (int nt = 0; nt < 4; ++nt) bm1v[nt] = wsb[nt * 16 + ln];
        float bm2v[2] = { wsb[64 + ln], wsb[80 + ln] };

#pragma unroll 2
        for (int et = 0; et < 8; ++et) {
            int e = et * 16 + ln;              // 0..127
            if (e >= 126) e = 0;               // pad rows: computed, never read
            const int dst  = (e < 63) ? e : e - 62;
            const int srcn = (e < 63) ? e + 1 : e - 63;
            const float* pd = xb + dst * 32 + q * 8;
            const float* ps = xb + srcn * 32 + q * 8;
            float4 d0 = *(const float4*)pd, d1 = *(const float4*)(pd + 4);
            float4 s0 = *(const float4*)ps, s1 = *(const float4*)(ps + 4);
            bf16x8 Ad = pack8(d0, d1);
            bf16x8 As = pack8(s0, s1);
            // A: h-tile [16 e][64] -> patch (bias folded into acc init)
#pragma unroll
            for (int nt = 0; nt < 4; ++nt) {
                f32x4 acc = {bm1v[nt], bm1v[nt], bm1v[nt], bm1v[nt]};
                acc = MFMA(Ad, B1a[nt], acc);
                acc = MFMA(As, B1b[nt], acc);
                const int c = nt * 16 + ln;
#pragma unroll
                for (int r = 0; r < 4; ++r)
                    patch[(q * 4 + r) * PS + c] = f2b(fmaxf(acc[r], 0.f));
            }
            // B: msgb-tile = relu(h @ Wm2 + bm2) -> mb  (same-wave LDS dep)
            bf16x8 A0 = __builtin_bit_cast(bf16x8, *(const uint4*)&patch[ln * PS + q * 8]);
            bf16x8 A1 = __builtin_bit_cast(bf16x8, *(const uint4*)&patch[ln * PS + 32 + q * 8]);
#pragma unroll
            for (int nt = 0; nt < 2; ++nt) {
                f32x4 acc = {bm2v[nt], bm2v[nt], bm2v[nt], bm2v[nt]};
                acc = MFMA(A0, B2[0][nt], acc);
                acc = MFMA(A1, B2[1][nt], acc);
                const int c = nt * 16 + ln;
#pragma unroll
                for (int r = 0; r < 4; ++r)
                    mb[(et * 16 + q * 4 + r) * MBS + c] = f2b(fmaxf(acc[r], 0.f));
            }
        }
    }

    // ===== Phases C+D, fused per 16-node tile =====
    {
        bf16x8 B3[2][4], B4[2][2];
#pragma unroll
        for (int s = 0; s < 2; ++s)
#pragma unroll
            for (int nt = 0; nt < 4; ++nt) B3[s][nt] = LDFRAG(12 + s * 4 + nt);
#pragma unroll
        for (int s = 0; s < 2; ++s)
#pragma unroll
            for (int nt = 0; nt < 2; ++nt) B4[s][nt] = LDFRAG(20 + s * 2 + nt);
        float bu1v[4];
#pragma unroll
        for (int nt = 0; nt < 4; ++nt) bu1v[nt] = wsb[96 + nt * 16 + ln];
        float bu2v[2] = { wsb[160 + ln], wsb[176 + ln] };
        const float rwv = wsb[192];
        const float om  = 1.f - rwv;

#pragma unroll 2
        for (int nt4 = 0; nt4 < 4; ++nt4) {
            const int row = nt4 * 16 + ln;     // node 0..63
            const float* p = xb + row * 32 + q * 8;
            float4 a0 = *(const float4*)p, a1 = *(const float4*)(p + 4);
            bf16x8 A0 = pack8(a0, a1);
            // gather + scatter-add messages: mb[row] + mb[62+row]
            float mv[8] = {0.f, 0.f, 0.f, 0.f, 0.f, 0.f, 0.f, 0.f};
            if (row < 63) {
                uint4 u = *(const uint4*)&mb[row * MBS + q * 8];
                const unsigned* pu = (const unsigned*)&u;
#pragma unroll
                for (int h = 0; h < 4; ++h) {
                    mv[2 * h]     += __uint_as_float(pu[h] << 16);
                    mv[2 * h + 1] += __uint_as_float(pu[h] & 0xFFFF0000u);
                }
            }
            if (row > 0) {
                uint4 u = *(const uint4*)&mb[(62 + row) * MBS + q * 8];
                const unsigned* pu = (const unsigned*)&u;
#pragma unroll
                for (int h = 0; h < 4; ++h) {
                    mv[2 * h]     += __uint_as_float(pu[h] << 16);
                    mv[2 * h + 1] += __uint_as_float(pu[h] & 0xFFFF0000u);
                }
            }
            bf16x8 A1;
#pragma unroll
            for (int j = 0; j < 8; ++j) A1[j] = (__bf16)mv[j];
            // C: hu-tile [16][64] -> patch
#pragma unroll
            for (int nt = 0; nt < 4; ++nt) {
                f32x4 acc = {bu1v[nt], bu1v[nt], bu1v[nt], bu1v[nt]};
                acc = MFMA(A0, B3[0][nt], acc);
                acc = MFMA(A1, B3[1][nt], acc);
                const int c = nt * 16 + ln;
#pragma unroll
                for (int r = 0; r < 4; ++r)
                    patch[(q * 4 + r) * PS + c] = f2b(fmaxf(acc[r], 0.f));
            }
            // D: out-tile = rw*(hu @ Wu2 + bu2) + (1-rw)*x  (same-wave LDS dep)
            bf16x8 H0 = __builtin_bit_cast(bf16x8, *(const uint4*)&patch[ln * PS + q * 8]);
            bf16x8 H1 = __builtin_bit_cast(bf16x8, *(const uint4*)&patch[ln * PS + 32 + q * 8]);
#pragma unroll
            for (int nt = 0; nt < 2; ++nt) {
                f32x4 acc = {bu2v[nt], bu2v[nt], bu2v[nt], bu2v[nt]};
                acc = MFMA(H0, B4[0][nt], acc);
                acc = MFMA(H1, B4[1][nt], acc);
                const int c = nt * 16 + ln;
#pragma unroll
                for (int r = 0; r < 4; ++r) {
                    const int off = (nt4 * 16 + q * 4 + r) * 32 + c;
                    ob[off] = rwv * acc[r] + om * xb[off];
                }
            }
        }
    }
#undef LDFRAG
}

extern "C" void kernel_launch(void* const* d_in, const int* in_sizes, int n_in,
                              void* d_out, int out_size, void* d_ws, size_t ws_size,
                              hipStream_t stream) {
    const float* x   = (const float*)d_in[0];
    const float* Wm1 = (const float*)d_in[1];
    const float* bm1 = (const float*)d_in[2];
    const float* Wm2 = (const float*)d_in[3];
    const float* bm2 = (const float*)d_in[4];
    const float* Wu1 = (const float*)d_in[5];
    const float* bu1 = (const float*)d_in[6];
    const float* Wu2 = (const float*)d_in[7];
    const float* bu2 = (const float*)d_in[8];
    const float* rw  = (const float*)d_in[9];
    float* out = (float*)d_out;

    u16*   wsf = (u16*)d_ws;
    float* wsb = (float*)((char*)d_ws + 24576);

    const int B = in_sizes[0] / (64 * 32);
    agn_prep<<<48, 256, 0, stream>>>(Wm1, bm1, Wm2, bm2, Wu1, bu1, Wu2, bu2, rw, wsf, wsb);
    agn_main<<<B / 4, 256, 0, stream>>>(x, wsf, wsb, out);
}